// Round 1
// baseline (353.054 us; speedup 1.0000x reference)
//
#include <hip/hip_runtime.h>

#define B_  64
#define D_  4096
#define S_  128
#define N_  256
#define KC_ 4
#define KPB (D_ / KC_)   // 1024 K per gram block
#define BK  64           // K-chunk staged in LDS

using short8   = __attribute__((ext_vector_type(8)))  short;
using floatx16 = __attribute__((ext_vector_type(16))) float;

__device__ __forceinline__ unsigned short f2bf(float f) {
  unsigned int u = __builtin_bit_cast(unsigned int, f);
  u = (u + 0x7FFFu + ((u >> 16) & 1u)) >> 16;   // round-to-nearest-even
  return (unsigned short)u;
}

// gram[b][n][m] += sum over this block's K-range of x[b][n][k]*x[b][m][k]
// x[b][n][k] = source[b][k][n] (n<128) or target[b][k][n-128]
__global__ __launch_bounds__(1024, 4) void k_gram(
    const float* __restrict__ src, const float* __restrict__ tgt,
    float* __restrict__ gram) {
  // swizzled [n][k] bf16 tile: row = 64 ushorts (128 B), 16B granule g stored
  // at position (g ^ (n&7)) -> conflict-free ds_read_b128 fragment reads.
  __shared__ unsigned short lds[N_ * BK];  // 32 KB
  const int kc  = blockIdx.x;
  const int b   = blockIdx.y;
  const int tid = threadIdx.x;
  const int l   = tid & 63;
  const int w   = tid >> 6;            // wave 0..15
  const int tr  = w >> 2, tc = w & 3;  // 4x4 grid of 64x64 wave tiles

  // staging role: thread owns one column n, 16 k's (4 groups of 4)
  const int n_s = tid & 255;
  const int kg  = tid >> 8;            // 0..3
  const float* colbase = (n_s < S_)
      ? (src + (size_t)b * D_ * S_ + n_s)
      : (tgt + (size_t)b * D_ * S_ + (n_s - S_));

  floatx16 acc[2][2];
  #pragma unroll
  for (int i = 0; i < 2; i++)
    #pragma unroll
    for (int j = 0; j < 2; j++)
      #pragma unroll
      for (int r = 0; r < 16; r++) acc[i][j][r] = 0.f;

  const int lm = l & 31;
  const int lk = l >> 5;               // 0/1
  const int am = tr * 64 + lm;         // A-frag row (sub adds 32)
  const int bm = tc * 64 + lm;         // B-frag col

  for (int ch = 0; ch < KPB / BK; ch++) {
    const int d0 = kc * KPB + ch * BK;
    __syncthreads();                   // LDS safe to overwrite
    #pragma unroll
    for (int kk = 0; kk < 16; kk += 4) {
      const int dd = d0 + kg * 16 + kk;
      float x0 = colbase[(size_t)(dd + 0) * S_];
      float x1 = colbase[(size_t)(dd + 1) * S_];
      float x2 = colbase[(size_t)(dd + 2) * S_];
      float x3 = colbase[(size_t)(dd + 3) * S_];
      unsigned int w0 = (unsigned int)f2bf(x0) | ((unsigned int)f2bf(x1) << 16);
      unsigned int w1 = (unsigned int)f2bf(x2) | ((unsigned int)f2bf(x3) << 16);
      const int klocal = kg * 16 + kk;
      const int g = klocal >> 3;
      const int a16 = n_s * 64 + ((g ^ (n_s & 7)) << 3) + (klocal & 7);
      *(uint2*)&lds[a16] = make_uint2(w0, w1);
    }
    __syncthreads();
    #pragma unroll
    for (int ks = 0; ks < 4; ks++) {
      const int koff = ks * 16 + lk * 8;
      const int g = koff >> 3;
      short8 a0 = *(const short8*)&lds[(am)      * 64 + ((g ^ (am & 7)) << 3)];
      short8 a1 = *(const short8*)&lds[(am + 32) * 64 + ((g ^ (am & 7)) << 3)];
      short8 b0 = *(const short8*)&lds[(bm)      * 64 + ((g ^ (bm & 7)) << 3)];
      short8 b1 = *(const short8*)&lds[(bm + 32) * 64 + ((g ^ (bm & 7)) << 3)];
      acc[0][0] = __builtin_amdgcn_mfma_f32_32x32x16_bf16(a0, b0, acc[0][0], 0, 0, 0);
      acc[0][1] = __builtin_amdgcn_mfma_f32_32x32x16_bf16(a0, b1, acc[0][1], 0, 0, 0);
      acc[1][0] = __builtin_amdgcn_mfma_f32_32x32x16_bf16(a1, b0, acc[1][0], 0, 0, 0);
      acc[1][1] = __builtin_amdgcn_mfma_f32_32x32x16_bf16(a1, b1, acc[1][1], 0, 0, 0);
    }
  }
  // epilogue: combine K-split partials via device-scope atomics
  float* gb = gram + (size_t)b * N_ * N_;
  #pragma unroll
  for (int i = 0; i < 2; i++)
    #pragma unroll
    for (int j = 0; j < 2; j++)
      #pragma unroll
      for (int r = 0; r < 16; r++) {
        const int row = (r & 3) + 8 * (r >> 2) + 4 * lk;  // verified C/D layout
        const int col = l & 31;
        const int nr = tr * 64 + i * 32 + row;
        const int nc = tc * 64 + j * 32 + col;
        atomicAdd(&gb[nr * N_ + nc], acc[i][j][r]);
      }
}

// bw[b] from gram: sum L2 = 2n*sum(diag) - 2*sum(gram); sq == diag(gram)
__global__ void k_bw(const float* __restrict__ gram, float* __restrict__ bw) {
  __shared__ float red[8];
  const int b = blockIdx.x;
  const int t = threadIdx.x;  // 256
  const float* gb = gram + (size_t)b * N_ * N_;
  float tot = 0.f, dia = 0.f;
  for (int i = 0; i < N_; i++) {
    float v = gb[i * N_ + t];
    tot += v;
    if (i == t) dia = v;
  }
  for (int off = 32; off; off >>= 1) {
    tot += __shfl_down(tot, off);
    dia += __shfl_down(dia, off);
  }
  const int wv = t >> 6, ln = t & 63;
  if (ln == 0) { red[wv] = tot; red[4 + wv] = dia; }
  __syncthreads();
  if (t == 0) {
    float T  = red[0] + red[1] + red[2] + red[3];
    float Dg = red[4] + red[5] + red[6] + red[7];
    float SL2 = 2.f * (float)N_ * Dg - 2.f * T;
    bw[b] = SL2 / (float)(N_ * N_ - N_) * 0.25f;  // / kernel_mul^(num//2)
  }
}

// quadrant-signed sum of sum_k exp(-L2/(bw*2^k)), atomically into out[0]
__global__ void k_exp(const float* __restrict__ gram, const float* __restrict__ bw,
                      float* __restrict__ out) {
  __shared__ float sq[N_];
  __shared__ float red[4];
  const int rc = blockIdx.x;   // row chunk 0..3 (64 rows each)
  const int b  = blockIdx.y;
  const int t  = threadIdx.x;  // 256
  const float* gb = gram + (size_t)b * N_ * N_;
  sq[t] = gb[t * N_ + t];
  __syncthreads();
  const float bwv = bw[b];
  float nb[5];
  #pragma unroll
  for (int k = 0; k < 5; k++)
    nb[k] = -1.4426950408889634f / (bwv * (float)(1 << k));
  const int col = t;
  const float sqc  = sq[col];
  const float csgn = (col < S_) ? 1.f : -1.f;
  float accv = 0.f;
  for (int i = 0; i < 64; i++) {
    const int row = rc * 64 + i;
    float g  = gb[row * N_ + col];
    float L2 = sq[row] + sqc - 2.f * g;
    float s = 0.f;
    #pragma unroll
    for (int k = 0; k < 5; k++) s += exp2f(L2 * nb[k]);
    accv += ((row < S_) ? csgn : -csgn) * s;
  }
  for (int off = 32; off; off >>= 1) accv += __shfl_down(accv, off);
  const int wv = t >> 6, ln = t & 63;
  if (ln == 0) red[wv] = accv;
  __syncthreads();
  if (t == 0) {
    float s = red[0] + red[1] + red[2] + red[3];
    atomicAdd(out, s * (1.0f / (64.f * 16384.f)));  // / (B * S*S)
  }
}

extern "C" void kernel_launch(void* const* d_in, const int* in_sizes, int n_in,
                              void* d_out, int out_size, void* d_ws, size_t ws_size,
                              hipStream_t stream) {
  const float* src = (const float*)d_in[0];
  const float* tgt = (const float*)d_in[1];
  const size_t gram_bytes = (size_t)B_ * N_ * N_ * sizeof(float);  // 16.8 MB
  float* gram = (float*)d_ws;
  float* bw   = (float*)((char*)d_ws + gram_bytes);
  hipMemsetAsync(gram, 0, gram_bytes, stream);
  hipMemsetAsync(d_out, 0, sizeof(float), stream);
  k_gram<<<dim3(KC_, B_), 1024, 0, stream>>>(src, tgt, gram);
  k_bw<<<B_, 256, 0, stream>>>(gram, bw);
  k_exp<<<dim3(4, B_), 256, 0, stream>>>(gram, bw, (float*)d_out);
}